// Round 1
// 223.424 us; speedup vs baseline: 1.1380x; 1.1380x over previous
//
#include <hip/hip_runtime.h>
#include <hip/hip_bf16.h>

typedef __attribute__((ext_vector_type(8))) short short8;
typedef __attribute__((ext_vector_type(4))) float floatx4;
typedef __attribute__((ext_vector_type(4))) unsigned int uintx4;

// fast GELU: x * (1 - 1/(exp(2u)+1)), u = 0.79788456*(x + 0.044715 x^3)
__device__ __forceinline__ float gelu_fast(float x)
{
    float u = 0.7978845608f * x * (1.0f + 0.044715f * x * x);
    float e = __builtin_amdgcn_exp2f(2.885390082f * u);   // exp(2u)
    return x - x * __builtin_amdgcn_rcpf(e + 1.0f);
}

// prep: [0,T): count triangles per dst, record slot; [T,T+6144): fragment-
// ordered bf16 W (frag f=ko*8+nt over global ko 0..11, lane l: 8 elems
// W[ko*32+quad*8+j][nt*16+col]).
__global__ __launch_bounds__(256)
void prep(const float* __restrict__ Wg, uintx4* __restrict__ wq,
          const int* __restrict__ tri, int* __restrict__ cnt,
          int* __restrict__ slot, int T)
{
    int g = blockIdx.x * 256 + threadIdx.x;
    if (g < T) {
        int i2 = tri[g * 3 + 2];
        slot[g] = atomicAdd(&cnt[i2], 1);
    } else {
        int i = g - T;
        if (i < 6144) {
            int frag = i >> 6, lane = i & 63;
            int ko = frag >> 3, nt = frag & 7;
            int col = lane & 15, quad = lane >> 4;
            unsigned short tmp[8] __attribute__((aligned(16)));
#pragma unroll
            for (int j = 0; j < 8; ++j) {
                __hip_bfloat16 b =
                    __float2bfloat16(Wg[(ko * 32 + quad * 8 + j) * 128 + nt * 16 + col]);
                tmp[j] = *(unsigned short*)&b;
            }
            wq[i] = *(const uintx4*)tmp;
        }
    }
}

__device__ __forceinline__ int wave_incl_scan(int v, int lane)
{
#pragma unroll
    for (int o = 1; o < 64; o <<= 1) {
        int u = __shfl_up(v, o);
        if (lane >= o) v += u;
    }
    return v;
}

// Block-level exclusive scan of 1024 elements; writes per-element exclusive
// prefix (within block) and block total to partial[] (if non-null).
__global__ __launch_bounds__(1024)
void scan_blk(const int* __restrict__ in, int* __restrict__ outExcl,
              int* __restrict__ partial, int n)
{
    __shared__ int ws[16];
    int t = threadIdx.x;
    int g = blockIdx.x * 1024 + t;
    int lane = t & 63, wv = t >> 6;
    int v = (g < n) ? in[g] : 0;
    int sc = wave_incl_scan(v, lane);
    if (lane == 63) ws[wv] = sc;
    __syncthreads();
    if (wv == 0) {
        int b = (lane < 16) ? ws[lane] : 0;
        int bs = wave_incl_scan(b, lane);
        if (lane < 16) ws[lane] = bs;
    }
    __syncthreads();
    int off = wv ? ws[wv - 1] : 0;
    if (g < n) outExcl[g] = off + sc - v;
    if (partial && t == 0) partial[blockIdx.x] = ws[15];
}

// Scatter triangles into dst-sorted order; store pre-scaled byte offsets.
__global__ __launch_bounds__(256)
void scatter(const int* __restrict__ tri, const int* __restrict__ slot,
             const int* __restrict__ excl, const int* __restrict__ pscan,
             int2* __restrict__ srec, int T)
{
    int g = blockIdx.x * 256 + threadIdx.x;
    if (g >= T) return;
    int i0 = tri[g * 3 + 0];
    int i1 = tri[g * 3 + 1];
    int i2 = tri[g * 3 + 2];
    int pos = excl[i2] + pscan[i2 >> 10] + slot[g];
    srec[pos] = make_int2(i0 << 8, i1 << 8);   // byte offsets into G rows
}

// One-pass dense GEMM: all 3 W slices resident in 96KB LDS; A tile loaded and
// converted once, used for r=0,1,2. Output bf16, permuted C-layout (row i:
// physical elem col*8+nt = logical col nt*16+col). No barriers in main loop.
__global__ __launch_bounds__(1024, 1)
void edge_gemm(const float* __restrict__ fe_f, const uintx4* __restrict__ wq,
               unsigned short* __restrict__ G, int E)
{
    __shared__ uintx4 ldsW[6144];   // 96 KB: 12 global-ko x 8 nt fragment blocks

    const int tid  = threadIdx.x;
    const int wv   = tid >> 6;
    const int lane = tid & 63;
    const int col  = lane & 15;
    const int quad = lane >> 4;
    const int ntiles = (E + 15) >> 4;

    for (int i = tid; i < 6144; i += 1024) ldsW[i] = wq[i];
    __syncthreads();

#pragma unroll 1
    for (int tile = blockIdx.x * 16 + wv; tile < ntiles; tile += gridDim.x * 16) {
        int row_a = tile * 16 + col;
        if (row_a >= E) row_a = E - 1;
        const float* arow = fe_f + (size_t)row_a * 128 + quad * 8;

        // load A once: 8 x float4 per lane, then convert to 4 bf16 fragments
        floatx4 f[8];
#pragma unroll
        for (int l = 0; l < 8; ++l)
            f[l] = *(const floatx4*)(arow + (l >> 1) * 32 + (l & 1) * 4);

        short8 a[4];
#pragma unroll
        for (int ko = 0; ko < 4; ++ko) {
            unsigned short tmp[8] __attribute__((aligned(16)));
#pragma unroll
            for (int j = 0; j < 8; ++j) {
                __hip_bfloat16 b = __float2bfloat16(f[ko * 2 + (j >> 2)][j & 3]);
                tmp[j] = *(unsigned short*)&b;
            }
            a[ko] = *(const short8*)tmp;
        }

#pragma unroll 1
        for (int r = 0; r < 3; ++r) {
            floatx4 acc[8];
#pragma unroll
            for (int nt = 0; nt < 8; ++nt) acc[nt] = (floatx4)0.0f;

#pragma unroll
            for (int ko = 0; ko < 4; ++ko) {
#pragma unroll
                for (int nt = 0; nt < 8; ++nt) {
                    short8 bf = *(const short8*)&ldsW[r * 2048 + (ko * 8 + nt) * 64 + lane];
                    acc[nt] = __builtin_amdgcn_mfma_f32_16x16x32_bf16(a[ko], bf, acc[nt], 0, 0, 0);
                }
            }

            unsigned short* Gr = G + (size_t)r * E * 128;
#pragma unroll
            for (int rr = 0; rr < 4; ++rr) {
                int row = tile * 16 + quad * 4 + rr;
                if (row < E) {
                    unsigned short pk[8] __attribute__((aligned(16)));
#pragma unroll
                    for (int nt = 0; nt < 8; ++nt) {
                        __hip_bfloat16 hb = __float2bfloat16(acc[nt][rr]);
                        pk[nt] = *(unsigned short*)&hb;
                    }
                    *(uintx4*)(Gr + (size_t)row * 128 + col * 8) = *(const uintx4*)pk;
                }
            }
        }
    }
}

// Per-edge fused gather + GELU + mean + LayerNorm, CSR version. One wave per
// edge. The wave loads up to 64 sorted records in ONE coalesced load and
// broadcasts via shfl; G2[row] + bias hoisted (i2 == row for whole chain).
// Lane (col,q) covers logical cols j0=32q+col, j1=j0+16 (permuted layout).
__global__ __launch_bounds__(256)
void mean_ln(const unsigned short* __restrict__ G, const int* __restrict__ cnt,
             const int* __restrict__ excl, const int* __restrict__ pscan,
             const int2* __restrict__ srec, const float* __restrict__ bias,
             const float* __restrict__ gamma, const float* __restrict__ beta,
             float* __restrict__ out, int E)
{
    int lane = threadIdx.x & 63;
    int row  = blockIdx.x * 4 + (threadIdx.x >> 6);
    if (row >= E) return;
    int col = lane & 15, q = lane >> 4;
    int boff = (col << 4) + (q << 2);   // byte offset within 256B row
    const char* g0 = (const char*)G + boff;
    const char* g1 = g0 + (size_t)E * 256;
    const char* g2 = g1 + (size_t)E * 256;
    int j0 = q * 32 + col, j1 = j0 + 16;

    unsigned int w2 = *(const unsigned int*)(g2 + (size_t)row * 256);
    float base0 = __uint_as_float(w2 << 16) + bias[j0];
    float base1 = __uint_as_float(w2 & 0xffff0000u) + bias[j1];

    int s = excl[row] + pscan[row >> 10];
    int c = cnt[row];

    float x0 = 0.0f, x1 = 0.0f;
    for (int p = 0; p < c; p += 64) {
        int nav = min(64, c - p);
        int2 rr = srec[s + p + (lane < nav ? lane : 0)];
        for (int k = 0; k < nav; ++k) {
            int o0 = __shfl(rr.x, k);
            int o1 = __shfl(rr.y, k);
            unsigned int w0 = *(const unsigned int*)(g0 + (size_t)(unsigned)o0);
            unsigned int w1 = *(const unsigned int*)(g1 + (size_t)(unsigned)o1);
            float s0 = __uint_as_float(w0 << 16) + __uint_as_float(w1 << 16) + base0;
            float s1 = __uint_as_float(w0 & 0xffff0000u)
                     + __uint_as_float(w1 & 0xffff0000u) + base1;
            x0 += gelu_fast(s0);
            x1 += gelu_fast(s1);
        }
    }

    float inv = 1.0f / fmaxf((float)c, 1.0f);
    float m0 = x0 * inv, m1 = x1 * inv;
    float sm = m0 + m1;
#pragma unroll
    for (int o = 32; o > 0; o >>= 1) sm += __shfl_xor(sm, o);
    float mu = sm * (1.0f / 128.0f);
    float d0 = m0 - mu, d1 = m1 - mu;
    float v = d0 * d0 + d1 * d1;
#pragma unroll
    for (int o = 32; o > 0; o >>= 1) v += __shfl_xor(v, o);
    float rstd = rsqrtf(v * (1.0f / 128.0f) + 1e-5f);
    out[(size_t)row * 128 + j0] = d0 * rstd * gamma[j0] + beta[j0];
    out[(size_t)row * 128 + j1] = d1 * rstd * gamma[j1] + beta[j1];
}

extern "C" void kernel_launch(void* const* d_in, const int* in_sizes, int n_in,
                              void* d_out, int out_size, void* d_ws, size_t ws_size,
                              hipStream_t stream)
{
    const float* fe_f  = (const float*)d_in[0];
    const float* Wg    = (const float*)d_in[1];
    const float* bias  = (const float*)d_in[2];
    const float* gamma = (const float*)d_in[3];
    const float* beta  = (const float*)d_in[4];
    const int*   tri   = (const int*)d_in[5];

    int E = in_sizes[0] / 128;
    int T = in_sizes[5] / 3;

    // ws: G (3*E*128 bf16) | srec (T int2) | wq (96KB) | slot (T i32) |
    //     cnt (E i32) | excl (E i32) | partial (1024 i32) | pscan (1024 i32)
    unsigned short* G = (unsigned short*)d_ws;
    int2* srec = (int2*)((char*)d_ws + (size_t)3 * E * 256);
    uintx4* wq = (uintx4*)(srec + T);
    int* slot = (int*)(wq + 6144);
    int* cnt  = slot + T;
    int* excl = cnt + E;
    int* partial = excl + E;
    int* pscan = partial + 1024;

    hipMemsetAsync(cnt, 0, (size_t)E * sizeof(int), stream);

    int total = T + 6144;
    prep<<<(total + 255) / 256, 256, 0, stream>>>(Wg, wq, tri, cnt, slot, T);

    int NB = (E + 1023) / 1024;   // 98 for E=100000 (must be <= 1024)
    scan_blk<<<NB, 1024, 0, stream>>>(cnt, excl, partial, E);
    scan_blk<<<1, 1024, 0, stream>>>(partial, pscan, nullptr, NB);

    scatter<<<(T + 255) / 256, 256, 0, stream>>>(tri, slot, excl, pscan, srec, T);

    edge_gemm<<<256, 1024, 0, stream>>>(fe_f, wq, G, E);

    mean_ln<<<(E + 3) / 4, 256, 0, stream>>>(G, cnt, excl, pscan, srec,
                                             bias, gamma, beta, (float*)d_out, E);
}